// Round 5
// baseline (168.678 us; speedup 1.0000x reference)
//
#include <hip/hip_runtime.h>
#include <stdint.h>

typedef _Float16 half8  __attribute__((ext_vector_type(8)));
typedef __fp16   fp16x2 __attribute__((ext_vector_type(2)));
typedef float    floatx4 __attribute__((ext_vector_type(4)));
typedef uint32_t u32x4  __attribute__((ext_vector_type(4)));
typedef float    f4a    __attribute__((ext_vector_type(4), aligned(4)));  // 4B-aligned 16B load

union FragU { u32x4 v; uint32_t u[4]; half8 h; };
union H2U   { fp16x2 h; uint32_t u; };

#define NT 256
#define NBLOCKS 2048

// ---------------- setup: build per-lane A-fragments (weights) into d_ws ----------------
// Step s=0: 64*W0 (7->12), bias 64*b0
// Steps 1..4: W1..W4 (12->12), bias 64*b
// Step 5: (W5@W6)/64 (12->1), bias b5@W6+b6
// A-frag layout for mfma_f32_16x16x32_f16: lane l holds A[m=l&15][k=(l>>4)*8+e], e=0..7.
// Interleaved K: k=2i   -> frag0 = w_hi, frag1 = w_lo
//                k=2i+1 -> frag0 = w_hi, frag1 = 0
// Bias slot: k=30 (g==3, w==3, low half): frag0 = bias_hi, frag1 = bias_lo (B supplies 1.0 there).
__global__ void build_frags(const float* __restrict__ W0, const float* __restrict__ b0,
                            const float* __restrict__ W1, const float* __restrict__ b1,
                            const float* __restrict__ W2, const float* __restrict__ b2,
                            const float* __restrict__ W3, const float* __restrict__ b3,
                            const float* __restrict__ W4, const float* __restrict__ b4,
                            const float* __restrict__ W5, const float* __restrict__ b5,
                            const float* __restrict__ W6, const float* __restrict__ b6,
                            uint32_t* __restrict__ ws)
{
    const int l = threadIdx.x;
    if (l >= 64) return;
    const int m = l & 15, g = l >> 4;
    const float* Wm[5] = {W0, W1, W2, W3, W4};
    const float* bm[5] = {b0, b1, b2, b3, b4};

    for (int s = 0; s < 6; ++s) {
        const int fan_in = (s == 0) ? 7 : 12;
        const int mmax   = (s == 5) ? 1 : 12;
        const float wscale = (s == 0) ? 64.0f : (s == 5 ? (1.0f / 64.0f) : 1.0f);
        for (int w = 0; w < 4; ++w) {
            const int i = g * 4 + w;
            uint32_t u1 = 0, u2 = 0;
            if (g == 3 && w == 3) {
                // bias slot (k=30 low half, k=31 high half=0)
                float bv = 0.0f;
                if (m < mmax) {
                    if (s == 5) { bv = b6[0]; for (int c = 0; c < 6; ++c) bv = fmaf(b5[c], W6[c], bv); }
                    else        { bv = 64.0f * bm[s][m]; }
                }
                H2U hh; hh.h = __builtin_amdgcn_cvt_pkrtz(bv, 0.0f);
                float hf = (float)hh.h[0];
                H2U ll; ll.h = __builtin_amdgcn_cvt_pkrtz(bv - hf, 0.0f);
                u1 = hh.u; u2 = ll.u;
            } else if (i < fan_in && m < mmax) {
                float wv;
                if (s == 5) { wv = 0.0f; for (int c = 0; c < 6; ++c) wv = fmaf(W5[i * 6 + c], W6[c], wv); wv *= wscale; }
                else        { wv = Wm[s][i * 12 + m] * wscale; }
                H2U hh; hh.h = __builtin_amdgcn_cvt_pkrtz(wv, wv);        // (w_hi, w_hi)
                float hf = (float)hh.h[0];
                H2U ll; ll.h = __builtin_amdgcn_cvt_pkrtz(wv - hf, 0.0f); // (w_lo, 0)
                u1 = hh.u; u2 = ll.u;
            }
            ws[((s * 2 + 0) * 64 + l) * 4 + w] = u1;
            ws[((s * 2 + 1) * 64 + l) * 4 + w] = u2;
        }
    }
}

// ---------------- main: 16 rows per wave-tile, grid-stride over tiles ----------------
__global__ __launch_bounds__(NT, 4) void mlp_mfma(const float* __restrict__ in,
                                                  const uint32_t* __restrict__ ws,
                                                  float* __restrict__ out,
                                                  int nrows, int nwaves)
{
    const int tid  = threadIdx.x;
    const int lane = tid & 63;
    const int wid  = (int)blockIdx.x * (NT / 64) + (tid >> 6);
    const int m = lane & 15, g = lane >> 4;
    const bool g1 = (g == 1), g3 = (g == 3), glt2 = (g < 2);

    // load all weight fragments once (48 VGPRs)
    half8 A[6][2];
    #pragma unroll
    for (int s = 0; s < 6; ++s)
        #pragma unroll
        for (int f = 0; f < 2; ++f) {
            FragU fu;
            fu.v = *(const u32x4*)(ws + ((s * 2 + f) * 64 + lane) * 4);
            A[s][f] = fu.h;
        }

    const int ntiles = nrows >> 4;
    int t = wid;
    if (t >= ntiles) return;

    // exact f16 hi/lo split, RTZ: low half = hi(y), high half = lo(y)
    auto SPLIT = [](float y) -> uint32_t {
        H2U a; a.h = __builtin_amdgcn_cvt_pkrtz(y, y);
        float hf = (float)a.h[0];
        H2U r; r.h = __builtin_amdgcn_cvt_pkrtz(y, y - hf);
        return r.u;
    };

    // prefetch first tile's input
    f4a q = {0.f, 0.f, 0.f, 0.f};
    {
        const int row = (t << 4) + m;
        if (glt2 && row < nrows) q = *(const f4a*)(in + row * 7 + (g1 ? 3 : 0));
    }

    while (t < ntiles) {
        const int row0 = t << 4;
        const int tn = t + nwaves;

        // ---- build L0 B-fragment from q (no relu on input) ----
        // g==0 supplies i=0..3 (q[0..3]); g==1 supplies i=4,5,6 (q[1..3]) and i=7 -> 0
        float v0 = g1 ? (float)q[1] : (float)q[0];
        float v1 = g1 ? (float)q[2] : (float)q[1];
        float v2 = g1 ? (float)q[3] : (float)q[2];
        float v3 = g1 ? 0.0f        : (float)q[3];
        FragU B;
        B.u[0] = SPLIT(v0);
        B.u[1] = SPLIT(v1);
        B.u[2] = SPLIT(v2);
        B.u[3] = g3 ? 0x00003C00u : SPLIT(v3);   // bias slot gets f16 1.0

        // ---- issue next tile's input load (hides under the 5 layer-steps) ----
        f4a qn = {0.f, 0.f, 0.f, 0.f};
        if (tn < ntiles) {
            const int row = (tn << 4) + m;
            if (glt2 && row < nrows) qn = *(const f4a*)(in + row * 7 + (g1 ? 3 : 0));
        }

        floatx4 acc = {0.f, 0.f, 0.f, 0.f};
        acc = __builtin_amdgcn_mfma_f32_16x16x32_f16(A[0][0], B.h, acc, 0, 0, 0);
        acc = __builtin_amdgcn_mfma_f32_16x16x32_f16(A[0][1], B.h, acc, 0, 0, 0);

        // ---- layer-steps 1..5; relu applies to outputs of layers 1..4 (i.e. prep for s>=2) ----
        #pragma unroll
        for (int s = 1; s <= 5; ++s) {
            float y0 = (s >= 2) ? fmaxf(acc[0], 0.f) : acc[0];
            float y1 = (s >= 2) ? fmaxf(acc[1], 0.f) : acc[1];
            float y2 = (s >= 2) ? fmaxf(acc[2], 0.f) : acc[2];
            float y3 = (s >= 2) ? fmaxf(acc[3], 0.f) : acc[3];
            B.u[0] = SPLIT(y0);
            B.u[1] = SPLIT(y1);
            B.u[2] = SPLIT(y2);
            B.u[3] = g3 ? 0x00003C00u : SPLIT(y3);
            floatx4 a2 = {0.f, 0.f, 0.f, 0.f};
            a2 = __builtin_amdgcn_mfma_f32_16x16x32_f16(A[s][0], B.h, a2, 0, 0, 0);
            a2 = __builtin_amdgcn_mfma_f32_16x16x32_f16(A[s][1], B.h, a2, 0, 0, 0);
            acc = a2;
        }

        // ---- output: D[m=0] lives in reg 0 of lanes 0..15 (n = row) ----
        if (lane < 16 && (row0 + m) < nrows) out[row0 + m] = acc[0];

        q = qn;
        t = tn;
    }
}

extern "C" void kernel_launch(void* const* d_in, const int* in_sizes, int n_in,
                              void* d_out, int out_size, void* d_ws, size_t ws_size,
                              hipStream_t stream) {
    const float* in = (const float*)d_in[0];
    const float* W0 = (const float*)d_in[1];  const float* b0 = (const float*)d_in[2];
    const float* W1 = (const float*)d_in[3];  const float* b1 = (const float*)d_in[4];
    const float* W2 = (const float*)d_in[5];  const float* b2 = (const float*)d_in[6];
    const float* W3 = (const float*)d_in[7];  const float* b3 = (const float*)d_in[8];
    const float* W4 = (const float*)d_in[9];  const float* b4 = (const float*)d_in[10];
    const float* W5 = (const float*)d_in[11]; const float* b5 = (const float*)d_in[12];
    const float* W6 = (const float*)d_in[13]; const float* b6 = (const float*)d_in[14];
    float* out = (float*)d_out;
    uint32_t* ws = (uint32_t*)d_ws;

    hipLaunchKernelGGL(build_frags, dim3(1), dim3(64), 0, stream,
                       W0, b0, W1, b1, W2, b2, W3, b3, W4, b4, W5, b5, W6, b6, ws);

    const int nrows = in_sizes[0] / 7;               // B*MS = 8388608
    const int nwaves = NBLOCKS * (NT / 64);
    hipLaunchKernelGGL(mlp_mfma, dim3(NBLOCKS), dim3(NT), 0, stream,
                       in, ws, out, nrows, nwaves);
}

// Round 7
// 141.432 us; speedup vs baseline: 1.1927x; 1.1927x over previous
//
#include <hip/hip_runtime.h>
#include <stdint.h>

typedef _Float16 half8  __attribute__((ext_vector_type(8)));
typedef __fp16   fp16x2 __attribute__((ext_vector_type(2)));
typedef float    floatx4 __attribute__((ext_vector_type(4)));
typedef uint32_t u32x4  __attribute__((ext_vector_type(4)));
typedef float    f4a    __attribute__((ext_vector_type(4), aligned(4)));  // 4B-aligned 16B load

union FragU { u32x4 v; uint32_t u[4]; half8 h; };
union H2U   { fp16x2 h; uint32_t u; };
union FU    { float f; uint32_t u; };

#define NT 256
#define NBLOCKS 1024                  // 4096 waves = 4 waves/SIMD resident
#define NWAVES (NBLOCKS * (NT / 64))  // 4096
#define ROWS_PER_GITER (NWAVES * 64)  // 262144

// Exact f16 hi/lo split, 3 VALU ops, no asm (proven numerics = round-5 path):
// RTZ f16 of in-range f32 == mantissa truncation, so mask top-10 mantissa bits.
// Returns u32 with lo16 = f16(hi part), hi16 = f16(y - hi)  [exact residual].
__device__ __forceinline__ uint32_t splitpk(float y) {
    FU a; a.f = y; a.u &= 0xFFFFE000u;        // hi = RTZ-f16-representable part
    H2U r; r.h = __builtin_amdgcn_cvt_pkrtz(a.f, y - a.f);
    return r.u;
}

// ---------------- setup: build per-lane A-fragments (weights) into d_ws ----------------
// Step s=0: 64*W0 (7->12), bias 64*b0; steps 1..4: W1..W4; step 5: (W5@W6)/64, bias b5@W6+b6.
// A-frag for mfma_f32_16x16x32_f16: lane l holds A[m=l&15][k=(l>>4)*8+e], e=0..7.
// Interleaved K: k=2i -> frag0=w_hi, frag1=w_lo ; k=2i+1 -> frag0=w_hi, frag1=0.
// Bias at k=30 (g==3,w==3): frag0=bias_hi, frag1=bias_lo (B supplies f16 1.0 there).
__global__ void build_frags(const float* __restrict__ W0, const float* __restrict__ b0,
                            const float* __restrict__ W1, const float* __restrict__ b1,
                            const float* __restrict__ W2, const float* __restrict__ b2,
                            const float* __restrict__ W3, const float* __restrict__ b3,
                            const float* __restrict__ W4, const float* __restrict__ b4,
                            const float* __restrict__ W5, const float* __restrict__ b5,
                            const float* __restrict__ W6, const float* __restrict__ b6,
                            uint32_t* __restrict__ ws)
{
    const int l = threadIdx.x;
    if (l >= 64) return;
    const int m = l & 15, g = l >> 4;
    const float* Wm[5] = {W0, W1, W2, W3, W4};
    const float* bm[5] = {b0, b1, b2, b3, b4};

    for (int s = 0; s < 6; ++s) {
        const int fan_in = (s == 0) ? 7 : 12;
        const int mmax   = (s == 5) ? 1 : 12;
        const float wscale = (s == 0) ? 64.0f : (s == 5 ? (1.0f / 64.0f) : 1.0f);
        for (int w = 0; w < 4; ++w) {
            const int i = g * 4 + w;
            uint32_t u1 = 0, u2 = 0;
            if (g == 3 && w == 3) {
                float bv = 0.0f;
                if (m < mmax) {
                    if (s == 5) { bv = b6[0]; for (int c = 0; c < 6; ++c) bv = fmaf(b5[c], W6[c], bv); }
                    else        { bv = 64.0f * bm[s][m]; }
                }
                H2U hh; hh.h = __builtin_amdgcn_cvt_pkrtz(bv, 0.0f);
                float hf = (float)hh.h[0];
                H2U ll; ll.h = __builtin_amdgcn_cvt_pkrtz(bv - hf, 0.0f);
                u1 = hh.u; u2 = ll.u;
            } else if (i < fan_in && m < mmax) {
                float wv;
                if (s == 5) { wv = 0.0f; for (int c = 0; c < 6; ++c) wv = fmaf(W5[i * 6 + c], W6[c], wv); wv *= wscale; }
                else        { wv = Wm[s][i * 12 + m] * wscale; }
                H2U hh; hh.h = __builtin_amdgcn_cvt_pkrtz(wv, wv);        // (w_hi, w_hi)
                float hf = (float)hh.h[0];
                H2U ll; ll.h = __builtin_amdgcn_cvt_pkrtz(wv - hf, 0.0f); // (w_lo, 0)
                u1 = hh.u; u2 = ll.u;
            }
            ws[((s * 2 + 0) * 64 + l) * 4 + w] = u1;
            ws[((s * 2 + 1) * 64 + l) * 4 + w] = u2;
        }
    }
}

// 4 independent 16-row MFMA chains: q[st] -> acc[st]
__device__ __forceinline__ void mlp16x4(const half8 (&A)[6][2], const f4a (&q)[4],
                                        floatx4 (&acc)[4], bool godd, bool g3)
{
    FragU B[4];
    #pragma unroll
    for (int st = 0; st < 4; ++st) {
        float v0 = godd ? (float)q[st][1] : (float)q[st][0];
        float v1 = godd ? (float)q[st][2] : (float)q[st][1];
        float v2 = godd ? (float)q[st][3] : (float)q[st][2];
        float v3 = godd ? 0.0f           : (float)q[st][3];
        B[st].u[0] = splitpk(v0);
        B[st].u[1] = splitpk(v1);
        B[st].u[2] = splitpk(v2);
        B[st].u[3] = g3 ? 0x00003C00u : splitpk(v3);   // bias slot: f16 1.0 at k=30
    }
    #pragma unroll
    for (int st = 0; st < 4; ++st) {
        floatx4 a = {0.f, 0.f, 0.f, 0.f};
        a = __builtin_amdgcn_mfma_f32_16x16x32_f16(A[0][0], B[st].h, a, 0, 0, 0);
        a = __builtin_amdgcn_mfma_f32_16x16x32_f16(A[0][1], B[st].h, a, 0, 0, 0);
        acc[st] = a;
    }
    #pragma unroll
    for (int s = 1; s <= 5; ++s) {
        #pragma unroll
        for (int st = 0; st < 4; ++st) {
            float y0 = acc[st][0], y1 = acc[st][1], y2 = acc[st][2], y3 = acc[st][3];
            if (s >= 2) {   // relu on outputs of layers 1..4
                y0 = fmaxf(y0, 0.f); y1 = fmaxf(y1, 0.f);
                y2 = fmaxf(y2, 0.f); y3 = fmaxf(y3, 0.f);
            }
            B[st].u[0] = splitpk(y0);
            B[st].u[1] = splitpk(y1);
            B[st].u[2] = splitpk(y2);
            B[st].u[3] = g3 ? 0x00003C00u : splitpk(y3);
        }
        #pragma unroll
        for (int st = 0; st < 4; ++st) {
            floatx4 a = {0.f, 0.f, 0.f, 0.f};
            a = __builtin_amdgcn_mfma_f32_16x16x32_f16(A[s][0], B[st].h, a, 0, 0, 0);
            a = __builtin_amdgcn_mfma_f32_16x16x32_f16(A[s][1], B[st].h, a, 0, 0, 0);
            acc[st] = a;
        }
    }
}

__global__ __launch_bounds__(NT, 4) void mlp_mfma(const float* __restrict__ in,
                                                  const uint32_t* __restrict__ ws,
                                                  float* __restrict__ out, int nrows)
{
    const int tid  = threadIdx.x;
    const int lane = tid & 63;
    const int m = lane & 15, g = lane >> 4;
    const bool godd = (g & 1) != 0;
    const bool g3   = (g == 3);

    // weight fragments: 48 VGPRs, loaded once
    half8 A[6][2];
    #pragma unroll
    for (int s = 0; s < 6; ++s)
        #pragma unroll
        for (int f = 0; f < 2; ++f) {
            FragU fu;
            fu.v = *(const u32x4*)(ws + ((s * 2 + f) * 64 + lane) * 4);
            A[s][f] = fu.h;
        }

    const int wid  = (int)blockIdx.x * (NT / 64) + (tid >> 6);
    const int wuid = __builtin_amdgcn_readfirstlane(wid);
    const float* inp = in  + (size_t)wuid * (64 * 7);
    float*      outp = out + (size_t)wuid * 64;
    const int voffx = m * 7 + (godd ? 3 : 0);   // even groups read x0..x3, odd read x3..x6

    const int niter = nrows / ROWS_PER_GITER;

    for (int t = 0; t < niter; ++t) {
        f4a q[4];
        #pragma unroll
        for (int st = 0; st < 4; ++st)
            q[st] = *(const f4a*)(inp + voffx + st * (16 * 7));   // +448B imm offsets

        floatx4 acc[4];
        mlp16x4(A, q, acc, godd, g3);

        if (lane < 16) {
            #pragma unroll
            for (int st = 0; st < 4; ++st)
                outp[st * 16 + m] = acc[st][0];
        }
        inp  += (size_t)ROWS_PER_GITER * 7;
        outp += ROWS_PER_GITER;
    }

    // tail (never taken for nrows = 8388608 = 32 * ROWS_PER_GITER; kept for safety)
    const int done = niter * ROWS_PER_GITER;
    if (done < nrows) {
        const int rowbase = done + wuid * 64;
        if (rowbase < nrows) {
            f4a q[4];
            #pragma unroll
            for (int st = 0; st < 4; ++st) {
                int row = rowbase + st * 16 + m;
                int rowc = row < nrows ? row : nrows - 1;
                q[st] = *(const f4a*)(in + (size_t)rowc * 7 + (godd ? 3 : 0));
            }
            floatx4 acc[4];
            mlp16x4(A, q, acc, godd, g3);
            if (lane < 16) {
                #pragma unroll
                for (int st = 0; st < 4; ++st) {
                    int row = rowbase + st * 16 + m;
                    if (row < nrows) out[row] = acc[st][0];
                }
            }
        }
    }
}

extern "C" void kernel_launch(void* const* d_in, const int* in_sizes, int n_in,
                              void* d_out, int out_size, void* d_ws, size_t ws_size,
                              hipStream_t stream) {
    const float* in = (const float*)d_in[0];
    const float* W0 = (const float*)d_in[1];  const float* b0 = (const float*)d_in[2];
    const float* W1 = (const float*)d_in[3];  const float* b1 = (const float*)d_in[4];
    const float* W2 = (const float*)d_in[5];  const float* b2 = (const float*)d_in[6];
    const float* W3 = (const float*)d_in[7];  const float* b3 = (const float*)d_in[8];
    const float* W4 = (const float*)d_in[9];  const float* b4 = (const float*)d_in[10];
    const float* W5 = (const float*)d_in[11]; const float* b5 = (const float*)d_in[12];
    const float* W6 = (const float*)d_in[13]; const float* b6 = (const float*)d_in[14];
    float* out = (float*)d_out;
    uint32_t* ws = (uint32_t*)d_ws;

    hipLaunchKernelGGL(build_frags, dim3(1), dim3(64), 0, stream,
                       W0, b0, W1, b1, W2, b2, W3, b3, W4, b4, W5, b5, W6, b6, ws);

    const int nrows = in_sizes[0] / 7;   // B*MS = 8388608
    hipLaunchKernelGGL(mlp_mfma, dim3(NBLOCKS), dim3(NT), 0, stream,
                       in, ws, out, nrows);
}

// Round 8
// 131.954 us; speedup vs baseline: 1.2783x; 1.0718x over previous
//
#include <hip/hip_runtime.h>
#include <stdint.h>

typedef _Float16 half8  __attribute__((ext_vector_type(8)));
typedef __fp16   fp16x2 __attribute__((ext_vector_type(2)));
typedef float    floatx4 __attribute__((ext_vector_type(4)));
typedef uint32_t u32x4  __attribute__((ext_vector_type(4)));
typedef float    f4a    __attribute__((ext_vector_type(4), aligned(4)));  // 4B-aligned 16B load

union FragU { u32x4 v; uint32_t u[4]; half8 h; };
union H2U   { fp16x2 h; uint32_t u; };
union FU    { float f; uint32_t u; };

#define NT 256
#define NBLOCKS 1024                  // 4096 waves = 4 waves/SIMD resident
#define NWAVES (NBLOCKS * (NT / 64))  // 4096
#define ROWS_PER_GITER (NWAVES * 64)  // 262144

// Exact f16 hi/lo split, 3 VALU ops (numerics proven in round 7):
// RTZ f16 of in-range f32 == mantissa truncation -> mask top-10 mantissa bits.
// Returns u32 with lo16 = f16(hi part), hi16 = f16(y - hi)  [exact residual].
__device__ __forceinline__ uint32_t splitpk(float y) {
    FU a; a.f = y; a.u &= 0xFFFFE000u;
    H2U r; r.h = __builtin_amdgcn_cvt_pkrtz(a.f, y - a.f);
    return r.u;
}

// ---------------- setup: build per-lane A-fragments (weights) into d_ws ----------------
// A-frag for mfma_f32_16x16x32_f16: lane l holds A[m=l&15][k=(l>>4)*8+e], e=0..7.
// Interleaved K: k=2i -> frag0=w_hi, frag1=w_lo ; k=2i+1 -> frag0=w_hi, frag1=0.
// Bias at k=30 (g==3,w==3): frag0=bias_hi, frag1=bias_lo (B supplies f16 1.0 there).
// L0 column table matches the lane load convention (even g: x0..x3 at +0; odd g: x3..x6 at +3):
//   g0 -> {x0,x1,x2,x3}, g1 -> {0(x3 dup), x4,x5,x6}, g2/g3 -> zeros (+bias slot).
__global__ void build_frags(const float* __restrict__ W0, const float* __restrict__ b0,
                            const float* __restrict__ W1, const float* __restrict__ b1,
                            const float* __restrict__ W2, const float* __restrict__ b2,
                            const float* __restrict__ W3, const float* __restrict__ b3,
                            const float* __restrict__ W4, const float* __restrict__ b4,
                            const float* __restrict__ W5, const float* __restrict__ b5,
                            const float* __restrict__ W6, const float* __restrict__ b6,
                            uint32_t* __restrict__ ws)
{
    const int l = threadIdx.x;
    if (l >= 64) return;
    const int m = l & 15, g = l >> 4;
    const float* Wm[5] = {W0, W1, W2, W3, W4};
    const float* bm[5] = {b0, b1, b2, b3, b4};

    for (int s = 0; s < 6; ++s) {
        const int fan_in = (s == 0) ? 7 : 12;
        const int mmax   = (s == 5) ? 1 : 12;
        const float wscale = (s == 0) ? 64.0f : (s == 5 ? (1.0f / 64.0f) : 1.0f);
        for (int w = 0; w < 4; ++w) {
            uint32_t u1 = 0, u2 = 0;
            if (g == 3 && w == 3) {
                float bv = 0.0f;
                if (m < mmax) {
                    if (s == 5) { bv = b6[0]; for (int c = 0; c < 6; ++c) bv = fmaf(b5[c], W6[c], bv); }
                    else        { bv = 64.0f * bm[s][m]; }
                }
                H2U hh; hh.h = __builtin_amdgcn_cvt_pkrtz(bv, 0.0f);
                float hf = (float)hh.h[0];
                H2U ll; ll.h = __builtin_amdgcn_cvt_pkrtz(bv - hf, 0.0f);
                u1 = hh.u; u2 = ll.u;
            } else {
                int i; bool ok;
                if (s == 0) { i = (g & 1) ? 3 + w : w; ok = ((g == 0) || (g == 1 && w > 0)) && (m < mmax); }
                else        { i = g * 4 + w;           ok = (i < fan_in) && (m < mmax); }
                if (ok) {
                    float wv;
                    if (s == 5) { wv = 0.0f; for (int c = 0; c < 6; ++c) wv = fmaf(W5[i * 6 + c], W6[c], wv); wv *= wscale; }
                    else        { wv = Wm[s][i * 12 + m] * wscale; }
                    H2U hh; hh.h = __builtin_amdgcn_cvt_pkrtz(wv, wv);        // (w_hi, w_hi)
                    float hf = (float)hh.h[0];
                    H2U ll; ll.h = __builtin_amdgcn_cvt_pkrtz(wv - hf, 0.0f); // (w_lo, 0)
                    u1 = hh.u; u2 = ll.u;
                }
            }
            ws[((s * 2 + 0) * 64 + l) * 4 + w] = u1;
            ws[((s * 2 + 1) * 64 + l) * 4 + w] = u2;
        }
    }
}

// 4 independent 16-row MFMA chains: q[st] -> acc[st].  B built per-subtile (low pressure).
__device__ __forceinline__ void mlp16x4(const half8 (&A)[6][2], const f4a (&q)[4],
                                        floatx4 (&acc)[4], bool g3)
{
    const floatx4 fzero = {0.f, 0.f, 0.f, 0.f};
    #pragma unroll
    for (int st = 0; st < 4; ++st) {
        FragU B;
        B.u[0] = splitpk(q[st][0]);
        B.u[1] = splitpk(q[st][1]);
        B.u[2] = splitpk(q[st][2]);
        B.u[3] = g3 ? 0x00003C00u : splitpk(q[st][3]);   // bias slot: f16 1.0 at k=30
        floatx4 a = fzero;
        a = __builtin_amdgcn_mfma_f32_16x16x32_f16(A[0][0], B.h, a, 0, 0, 0);
        a = __builtin_amdgcn_mfma_f32_16x16x32_f16(A[0][1], B.h, a, 0, 0, 0);
        acc[st] = a;
    }
    #pragma unroll
    for (int s = 1; s <= 5; ++s) {
        #pragma unroll
        for (int st = 0; st < 4; ++st) {
            float y0 = acc[st][0], y1 = acc[st][1], y2 = acc[st][2], y3 = acc[st][3];
            if (s >= 2) {   // relu on outputs of layers 1..4
                y0 = fmaxf(y0, 0.f); y1 = fmaxf(y1, 0.f);
                y2 = fmaxf(y2, 0.f); y3 = fmaxf(y3, 0.f);
            }
            FragU B;
            B.u[0] = splitpk(y0);
            B.u[1] = splitpk(y1);
            B.u[2] = splitpk(y2);
            B.u[3] = g3 ? 0x00003C00u : splitpk(y3);
            floatx4 a = fzero;
            a = __builtin_amdgcn_mfma_f32_16x16x32_f16(A[s][0], B.h, a, 0, 0, 0);
            a = __builtin_amdgcn_mfma_f32_16x16x32_f16(A[s][1], B.h, a, 0, 0, 0);
            acc[st] = a;
        }
    }
}

__global__ __launch_bounds__(NT, 4) void mlp_mfma(const float* __restrict__ in,
                                                  const uint32_t* __restrict__ ws,
                                                  float* __restrict__ out, int nrows)
{
    const int tid  = threadIdx.x;
    const int lane = tid & 63;
    const int m = lane & 15, g = lane >> 4;
    const bool godd = (g & 1) != 0;
    const bool g3   = (g == 3);

    // weight fragments: 48 regs (compiler places in AGPRs; MFMA-A reads are free)
    half8 A[6][2];
    #pragma unroll
    for (int s = 0; s < 6; ++s)
        #pragma unroll
        for (int f = 0; f < 2; ++f) {
            FragU fu;
            fu.v = *(const u32x4*)(ws + ((s * 2 + f) * 64 + lane) * 4);
            A[s][f] = fu.h;
        }

    const int wid  = (int)blockIdx.x * (NT / 64) + (tid >> 6);
    const int wuid = __builtin_amdgcn_readfirstlane(wid);
    const float* inp = in  + (size_t)wuid * (64 * 7);
    float*      outp = out + (size_t)wuid * 64;
    const int voffx = m * 7 + (godd ? 3 : 0);   // even groups x0..x3, odd groups x3..x6

    const int niter = nrows / ROWS_PER_GITER;
    const size_t S7 = (size_t)ROWS_PER_GITER * 7;

#define LOADQ(dst, base) { \
    _Pragma("unroll") \
    for (int st = 0; st < 4; ++st) dst[st] = *(const f4a*)((base) + voffx + st * (16 * 7)); }

    if (niter > 0) {
        f4a qa[4], qb[4];
        LOADQ(qa, inp);
        for (int t = 0; t < niter; t += 2) {
            const float* p1 = (t + 1 < niter) ? (inp + S7) : inp;   // clamped prefetch addr
            LOADQ(qb, p1);
            floatx4 acc[4];
            mlp16x4(A, qa, acc, g3);
            if (lane < 16) {
                #pragma unroll
                for (int st = 0; st < 4; ++st) outp[st * 16 + m] = acc[st][0];
            }
            const float* p2 = (t + 2 < niter) ? (inp + 2 * S7) : inp;
            LOADQ(qa, p2);
            if (t + 1 < niter) {
                mlp16x4(A, qb, acc, g3);
                if (lane < 16) {
                    #pragma unroll
                    for (int st = 0; st < 4; ++st) (outp + ROWS_PER_GITER)[st * 16 + m] = acc[st][0];
                }
            }
            inp  += 2 * S7;
            outp += 2 * (size_t)ROWS_PER_GITER;
        }
    }

    // tail (never taken for nrows = 8388608 = 32 * ROWS_PER_GITER; kept for safety)
    const int done = niter * ROWS_PER_GITER;
    if (done < nrows) {
        const int rowbase = done + wuid * 64;
        if (rowbase < nrows) {
            f4a q[4];
            #pragma unroll
            for (int st = 0; st < 4; ++st) {
                int row = rowbase + st * 16 + m;
                int rowc = row < nrows ? row : nrows - 1;
                q[st] = *(const f4a*)(in + (size_t)rowc * 7 + (godd ? 3 : 0));
            }
            floatx4 acc[4];
            mlp16x4(A, q, acc, g3);
            if (lane < 16) {
                #pragma unroll
                for (int st = 0; st < 4; ++st) {
                    int row = rowbase + st * 16 + m;
                    if (row < nrows) out[row] = acc[st][0];
                }
            }
        }
    }
#undef LOADQ
}

extern "C" void kernel_launch(void* const* d_in, const int* in_sizes, int n_in,
                              void* d_out, int out_size, void* d_ws, size_t ws_size,
                              hipStream_t stream) {
    const float* in = (const float*)d_in[0];
    const float* W0 = (const float*)d_in[1];  const float* b0 = (const float*)d_in[2];
    const float* W1 = (const float*)d_in[3];  const float* b1 = (const float*)d_in[4];
    const float* W2 = (const float*)d_in[5];  const float* b2 = (const float*)d_in[6];
    const float* W3 = (const float*)d_in[7];  const float* b3 = (const float*)d_in[8];
    const float* W4 = (const float*)d_in[9];  const float* b4 = (const float*)d_in[10];
    const float* W5 = (const float*)d_in[11]; const float* b5 = (const float*)d_in[12];
    const float* W6 = (const float*)d_in[13]; const float* b6 = (const float*)d_in[14];
    float* out = (float*)d_out;
    uint32_t* ws = (uint32_t*)d_ws;

    hipLaunchKernelGGL(build_frags, dim3(1), dim3(64), 0, stream,
                       W0, b0, W1, b1, W2, b2, W3, b3, W4, b4, W5, b5, W6, b6, ws);

    const int nrows = in_sizes[0] / 7;   // B*MS = 8388608
    hipLaunchKernelGGL(mlp_mfma, dim3(NBLOCKS), dim3(NT), 0, stream,
                       in, ws, out, nrows);
}

// Round 9
// 130.807 us; speedup vs baseline: 1.2895x; 1.0088x over previous
//
#include <hip/hip_runtime.h>
#include <stdint.h>

typedef _Float16 half8  __attribute__((ext_vector_type(8)));
typedef __fp16   fp16x2 __attribute__((ext_vector_type(2)));
typedef float    floatx4 __attribute__((ext_vector_type(4)));
typedef uint32_t u32x4  __attribute__((ext_vector_type(4)));
typedef float    f4a    __attribute__((ext_vector_type(4), aligned(4)));  // 4B-aligned 16B load

union FragU { u32x4 v; uint32_t u[4]; half8 h; };
union H2U   { fp16x2 h; uint32_t u; };
union FU    { float f; uint32_t u; };

#define NT 256
#define NBLOCKS 1024                  // 4096 waves = 4 waves/SIMD resident
#define NWAVES (NBLOCKS * (NT / 64))  // 4096
#define ROWS_PER_GITER (NWAVES * 64)  // 262144

// Exact f16 hi/lo split, 3 VALU ops (numerics proven in rounds 5/7/8):
// RTZ f16 of in-range f32 == mantissa truncation -> mask top-10 mantissa bits.
// Returns u32 with lo16 = f16(hi part), hi16 = f16(y - hi)  [exact residual].
__device__ __forceinline__ uint32_t splitpk(float y) {
    FU a; a.f = y; a.u &= 0xFFFFE000u;
    H2U r; r.h = __builtin_amdgcn_cvt_pkrtz(a.f, y - a.f);
    return r.u;
}

// ---------------- setup: build per-lane A-fragments (weights) into d_ws ----------------
// A-frag for mfma_f32_16x16x32_f16: lane l holds A[m=l&15][k=(l>>4)*8+e], e=0..7.
// Interleaved K: k=2i -> frag0=w_hi, frag1=w_lo ; k=2i+1 -> frag0=w_hi, frag1=0.
// Bias at k=30 (g==3,w==3): frag0=bias_hi, frag1=bias_lo (B supplies f16 1.0 there).
// L0 column table matches the lane load convention (even g: x0..x3 at +0; odd g: x3..x6 at +3):
//   g0 -> {x0,x1,x2,x3}, g1 -> {0(x3 dup), x4,x5,x6}, g2/g3 -> zeros (+bias slot).
__global__ void build_frags(const float* __restrict__ W0, const float* __restrict__ b0,
                            const float* __restrict__ W1, const float* __restrict__ b1,
                            const float* __restrict__ W2, const float* __restrict__ b2,
                            const float* __restrict__ W3, const float* __restrict__ b3,
                            const float* __restrict__ W4, const float* __restrict__ b4,
                            const float* __restrict__ W5, const float* __restrict__ b5,
                            const float* __restrict__ W6, const float* __restrict__ b6,
                            uint32_t* __restrict__ ws)
{
    const int l = threadIdx.x;
    if (l >= 64) return;
    const int m = l & 15, g = l >> 4;
    const float* Wm[5] = {W0, W1, W2, W3, W4};
    const float* bm[5] = {b0, b1, b2, b3, b4};

    for (int s = 0; s < 6; ++s) {
        const int fan_in = (s == 0) ? 7 : 12;
        const int mmax   = (s == 5) ? 1 : 12;
        const float wscale = (s == 0) ? 64.0f : (s == 5 ? (1.0f / 64.0f) : 1.0f);
        for (int w = 0; w < 4; ++w) {
            uint32_t u1 = 0, u2 = 0;
            if (g == 3 && w == 3) {
                float bv = 0.0f;
                if (m < mmax) {
                    if (s == 5) { bv = b6[0]; for (int c = 0; c < 6; ++c) bv = fmaf(b5[c], W6[c], bv); }
                    else        { bv = 64.0f * bm[s][m]; }
                }
                H2U hh; hh.h = __builtin_amdgcn_cvt_pkrtz(bv, 0.0f);
                float hf = (float)hh.h[0];
                H2U ll; ll.h = __builtin_amdgcn_cvt_pkrtz(bv - hf, 0.0f);
                u1 = hh.u; u2 = ll.u;
            } else {
                int i; bool ok;
                if (s == 0) { i = (g & 1) ? 3 + w : w; ok = ((g == 0) || (g == 1 && w > 0)) && (m < mmax); }
                else        { i = g * 4 + w;           ok = (i < fan_in) && (m < mmax); }
                if (ok) {
                    float wv;
                    if (s == 5) { wv = 0.0f; for (int c = 0; c < 6; ++c) wv = fmaf(W5[i * 6 + c], W6[c], wv); wv *= wscale; }
                    else        { wv = Wm[s][i * 12 + m] * wscale; }
                    H2U hh; hh.h = __builtin_amdgcn_cvt_pkrtz(wv, wv);        // (w_hi, w_hi)
                    float hf = (float)hh.h[0];
                    H2U ll; ll.h = __builtin_amdgcn_cvt_pkrtz(wv - hf, 0.0f); // (w_lo, 0)
                    u1 = hh.u; u2 = ll.u;
                }
            }
            ws[((s * 2 + 0) * 64 + l) * 4 + w] = u1;
            ws[((s * 2 + 1) * 64 + l) * 4 + w] = u2;
        }
    }
}

// 4 independent 16-row MFMA chains: q[st] -> acc[st].  B built per-subtile (low pressure).
__device__ __forceinline__ void mlp16x4(const half8 (&A)[6][2], const f4a (&q)[4],
                                        floatx4 (&acc)[4], bool g3)
{
    const floatx4 fzero = {0.f, 0.f, 0.f, 0.f};
    #pragma unroll
    for (int st = 0; st < 4; ++st) {
        FragU B;
        B.u[0] = splitpk(q[st][0]);
        B.u[1] = splitpk(q[st][1]);
        B.u[2] = splitpk(q[st][2]);
        B.u[3] = g3 ? 0x00003C00u : splitpk(q[st][3]);   // bias slot: f16 1.0 at k=30
        floatx4 a = fzero;
        a = __builtin_amdgcn_mfma_f32_16x16x32_f16(A[0][0], B.h, a, 0, 0, 0);
        a = __builtin_amdgcn_mfma_f32_16x16x32_f16(A[0][1], B.h, a, 0, 0, 0);
        acc[st] = a;
    }
    #pragma unroll
    for (int s = 1; s <= 5; ++s) {
        #pragma unroll
        for (int st = 0; st < 4; ++st) {
            float y0 = acc[st][0], y1 = acc[st][1], y2 = acc[st][2], y3 = acc[st][3];
            if (s >= 2) {   // relu on outputs of layers 1..4
                y0 = fmaxf(y0, 0.f); y1 = fmaxf(y1, 0.f);
                y2 = fmaxf(y2, 0.f); y3 = fmaxf(y3, 0.f);
            }
            FragU B;
            B.u[0] = splitpk(y0);
            B.u[1] = splitpk(y1);
            B.u[2] = splitpk(y2);
            B.u[3] = g3 ? 0x00003C00u : splitpk(y3);
            floatx4 a = fzero;
            a = __builtin_amdgcn_mfma_f32_16x16x32_f16(A[s][0], B.h, a, 0, 0, 0);
            a = __builtin_amdgcn_mfma_f32_16x16x32_f16(A[s][1], B.h, a, 0, 0, 0);
            acc[st] = a;
        }
    }
}

__global__ __launch_bounds__(NT, 4) void mlp_mfma(const float* __restrict__ in,
                                                  const uint32_t* __restrict__ ws,
                                                  float* __restrict__ out, int nrows)
{
    const int tid  = threadIdx.x;
    const int lane = tid & 63;
    const int m = lane & 15, g = lane >> 4;
    const bool godd = (g & 1) != 0;
    const bool g3   = (g == 3);

    // weight fragments: 48 regs (compiler places in AGPRs; MFMA-A reads are free)
    half8 A[6][2];
    #pragma unroll
    for (int s = 0; s < 6; ++s)
        #pragma unroll
        for (int f = 0; f < 2; ++f) {
            FragU fu;
            fu.v = *(const u32x4*)(ws + ((s * 2 + f) * 64 + lane) * 4);
            A[s][f] = fu.h;
        }

    const int wid  = (int)blockIdx.x * (NT / 64) + (tid >> 6);
    const int wuid = __builtin_amdgcn_readfirstlane(wid);
    const float* inp = in  + (size_t)wuid * (64 * 7);
    float*      outp = out + (size_t)wuid * 64;
    const int voffx = m * 7 + (godd ? 3 : 0);   // even groups x0..x3, odd groups x3..x6

    const int niter = nrows / ROWS_PER_GITER;
    const size_t S7 = (size_t)ROWS_PER_GITER * 7;

#define LOADQ(dst, base) { \
    _Pragma("unroll") \
    for (int st = 0; st < 4; ++st) dst[st] = *(const f4a*)((base) + voffx + st * (16 * 7)); }

    if (niter > 0) {
        f4a qa[4], qb[4];
        LOADQ(qa, inp);
        for (int t = 0; t < niter; t += 2) {
            const float* p1 = (t + 1 < niter) ? (inp + S7) : inp;   // clamped prefetch addr
            LOADQ(qb, p1);

            floatx4 accA[4];
            mlp16x4(A, qa, accA, g3);

            // CRITICAL ORDER: issue next loads BEFORE this giter's stores.
            // vmcnt retires in issue order; if stores precede the loads, every
            // later wait-for-load also waits for the stores' L2 ack (~400 cyc).
            const float* p2 = (t + 2 < niter) ? (inp + 2 * S7) : inp;
            LOADQ(qa, p2);

            if (lane < 16) {
                #pragma unroll
                for (int st = 0; st < 4; ++st) outp[st * 16 + m] = accA[st][0];
            }

            if (t + 1 < niter) {
                floatx4 accB[4];
                mlp16x4(A, qb, accB, g3);
                if (lane < 16) {
                    #pragma unroll
                    for (int st = 0; st < 4; ++st) (outp + ROWS_PER_GITER)[st * 16 + m] = accB[st][0];
                }
            }
            inp  += 2 * S7;
            outp += 2 * (size_t)ROWS_PER_GITER;
        }
    }

    // tail (never taken for nrows = 8388608 = 32 * ROWS_PER_GITER; kept for safety)
    const int done = niter * ROWS_PER_GITER;
    if (done < nrows) {
        const int rowbase = done + wuid * 64;
        if (rowbase < nrows) {
            f4a q[4];
            #pragma unroll
            for (int st = 0; st < 4; ++st) {
                int row = rowbase + st * 16 + m;
                int rowc = row < nrows ? row : nrows - 1;
                q[st] = *(const f4a*)(in + (size_t)rowc * 7 + (godd ? 3 : 0));
            }
            floatx4 acc[4];
            mlp16x4(A, q, acc, g3);
            if (lane < 16) {
                #pragma unroll
                for (int st = 0; st < 4; ++st) {
                    int row = rowbase + st * 16 + m;
                    if (row < nrows) out[row] = acc[st][0];
                }
            }
        }
    }
#undef LOADQ
}

extern "C" void kernel_launch(void* const* d_in, const int* in_sizes, int n_in,
                              void* d_out, int out_size, void* d_ws, size_t ws_size,
                              hipStream_t stream) {
    const float* in = (const float*)d_in[0];
    const float* W0 = (const float*)d_in[1];  const float* b0 = (const float*)d_in[2];
    const float* W1 = (const float*)d_in[3];  const float* b1 = (const float*)d_in[4];
    const float* W2 = (const float*)d_in[5];  const float* b2 = (const float*)d_in[6];
    const float* W3 = (const float*)d_in[7];  const float* b3 = (const float*)d_in[8];
    const float* W4 = (const float*)d_in[9];  const float* b4 = (const float*)d_in[10];
    const float* W5 = (const float*)d_in[11]; const float* b5 = (const float*)d_in[12];
    const float* W6 = (const float*)d_in[13]; const float* b6 = (const float*)d_in[14];
    float* out = (float*)d_out;
    uint32_t* ws = (uint32_t*)d_ws;

    hipLaunchKernelGGL(build_frags, dim3(1), dim3(64), 0, stream,
                       W0, b0, W1, b1, W2, b2, W3, b3, W4, b4, W5, b5, W6, b6, ws);

    const int nrows = in_sizes[0] / 7;   // B*MS = 8388608
    hipLaunchKernelGGL(mlp_mfma, dim3(NBLOCKS), dim3(NT), 0, stream,
                       in, ws, out, nrows);
}